// Round 1
// baseline (896.544 us; speedup 1.0000x reference)
//
#include <hip/hip_runtime.h>

#define NB 32
#define NN 1024
#define FIN 512
#define HH1 256
#define HH2 128

__device__ __forceinline__ float leakyf(float x) { return x >= 0.0f ? x : 0.01f * x; }
__device__ __forceinline__ float sigm(float x) { return 1.0f / (1.0f + __expf(-x)); }
__device__ __forceinline__ float eluf(float x) { return x > 0.0f ? x : __expf(x) - 1.0f; }

// ---------------------------------------------------------------------------
// Plain fp32 GEMM: C[M,Nc] = A[M,K] @ Bw[K,Nc], row-major, M%64==0, K%16==0,
// Nc%64==0. 64x64 tile, 256 threads, 4x4 micro-tile.
// ---------------------------------------------------------------------------
__global__ __launch_bounds__(256) void gemm_plain(const float* __restrict__ A,
                                                  const float* __restrict__ Bw,
                                                  float* __restrict__ C,
                                                  int K, int Nc) {
  __shared__ float As[16][68];   // [k][m], pad 68 -> conflict-free
  __shared__ float Bs[16][64];   // [k][n]
  const int t  = threadIdx.x;
  const int tx = t & 15, ty = t >> 4;
  const int m0 = blockIdx.x * 64;
  const int n0 = blockIdx.y * 64;
  const int la_m = t >> 2;           // 0..63
  const int la_k = (t & 3) << 2;     // 0,4,8,12
  const int lb_k = t >> 4;           // 0..15
  const int lb_c = (t & 15) << 2;    // 0..60
  float acc[4][4] = {{0.f}};
  const float* Ap = A + (size_t)(m0 + la_m) * K + la_k;
  const float* Bp = Bw + (size_t)lb_k * Nc + n0 + lb_c;
  for (int k0 = 0; k0 < K; k0 += 16) {
    float4 av = *(const float4*)(Ap + k0);
    float4 bv = *(const float4*)(Bp + (size_t)k0 * Nc);
    __syncthreads();
    As[la_k + 0][la_m] = av.x;
    As[la_k + 1][la_m] = av.y;
    As[la_k + 2][la_m] = av.z;
    As[la_k + 3][la_m] = av.w;
    *(float4*)&Bs[lb_k][lb_c] = bv;
    __syncthreads();
#pragma unroll
    for (int k = 0; k < 16; ++k) {
      float4 a = *(const float4*)&As[k][ty << 2];
      float4 b = *(const float4*)&Bs[k][tx << 2];
      acc[0][0] += a.x * b.x; acc[0][1] += a.x * b.y; acc[0][2] += a.x * b.z; acc[0][3] += a.x * b.w;
      acc[1][0] += a.y * b.x; acc[1][1] += a.y * b.y; acc[1][2] += a.y * b.z; acc[1][3] += a.y * b.w;
      acc[2][0] += a.z * b.x; acc[2][1] += a.z * b.y; acc[2][2] += a.z * b.z; acc[2][3] += a.z * b.w;
      acc[3][0] += a.w * b.x; acc[3][1] += a.w * b.y; acc[3][2] += a.w * b.z; acc[3][3] += a.w * b.w;
    }
  }
#pragma unroll
  for (int i = 0; i < 4; ++i) {
    float4 v = make_float4(acc[i][0], acc[i][1], acc[i][2], acc[i][3]);
    *(float4*)&C[(size_t)(m0 + (ty << 2) + i) * Nc + n0 + (tx << 2)] = v;
  }
}

// ---------------------------------------------------------------------------
// Attention GEMM (per batch): C[i,f] = sum_j att(i,j) * Bmat[j,f]
// att(i,j) = sigmoid((leaky(el_i + er_j) - mn)*inv - 20), synthesized in LDS.
// act==1 -> elu epilogue. M=K=NN, Nc in {128,256}.
// ---------------------------------------------------------------------------
__global__ __launch_bounds__(256) void gemm_att(const float* __restrict__ el,
                                                const float* __restrict__ er,
                                                const float2* __restrict__ params,
                                                const float* __restrict__ Bmat,
                                                float* __restrict__ C,
                                                int Nc, int act) {
  __shared__ float As[16][68];
  __shared__ float Bs[16][64];
  const int b  = blockIdx.z;
  const int t  = threadIdx.x;
  const int tx = t & 15, ty = t >> 4;
  const int m0 = blockIdx.x * 64;
  const int n0 = blockIdx.y * 64;
  const float2 p = params[b];
  const float* elb = el + b * NN;
  const float* erb = er + b * NN;
  const float* Bb  = Bmat + (size_t)b * NN * Nc;
  float* Cb        = C + (size_t)b * NN * Nc;
  const int fa_r = t >> 4;   // 0..15
  const int fa_c = t & 15;   // 0..15
  float elr[4];
#pragma unroll
  for (int it = 0; it < 4; ++it) elr[it] = elb[m0 + fa_r + (it << 4)];
  const int lb_k = t >> 4;
  const int lb_c = (t & 15) << 2;
  const float* Bp = Bb + (size_t)lb_k * Nc + n0 + lb_c;
  float acc[4][4] = {{0.f}};
  for (int k0 = 0; k0 < NN; k0 += 16) {
    float erv = erb[k0 + fa_c];
    float4 bv = *(const float4*)(Bp + (size_t)k0 * Nc);
    __syncthreads();
#pragma unroll
    for (int it = 0; it < 4; ++it) {
      float e = (leakyf(elr[it] + erv) - p.x) * p.y - 20.0f;
      As[fa_c][fa_r + (it << 4)] = sigm(e);
    }
    *(float4*)&Bs[lb_k][lb_c] = bv;
    __syncthreads();
#pragma unroll
    for (int k = 0; k < 16; ++k) {
      float4 a = *(const float4*)&As[k][ty << 2];
      float4 b2 = *(const float4*)&Bs[k][tx << 2];
      acc[0][0] += a.x * b2.x; acc[0][1] += a.x * b2.y; acc[0][2] += a.x * b2.z; acc[0][3] += a.x * b2.w;
      acc[1][0] += a.y * b2.x; acc[1][1] += a.y * b2.y; acc[1][2] += a.y * b2.z; acc[1][3] += a.y * b2.w;
      acc[2][0] += a.z * b2.x; acc[2][1] += a.z * b2.y; acc[2][2] += a.z * b2.z; acc[2][3] += a.z * b2.w;
      acc[3][0] += a.w * b2.x; acc[3][1] += a.w * b2.y; acc[3][2] += a.w * b2.z; acc[3][3] += a.w * b2.w;
    }
  }
#pragma unroll
  for (int i = 0; i < 4; ++i) {
    float4 v = make_float4(acc[i][0], acc[i][1], acc[i][2], acc[i][3]);
    if (act) { v.x = eluf(v.x); v.y = eluf(v.y); v.z = eluf(v.z); v.w = eluf(v.w); }
    *(float4*)&Cb[(size_t)(m0 + (ty << 2) + i) * Nc + n0 + (tx << 2)] = v;
  }
}

// ---------------------------------------------------------------------------
// el/er: two dot products per row. One wave per row, R rows total = grid*4.
// ---------------------------------------------------------------------------
__global__ __launch_bounds__(256) void rowdot2(const float* __restrict__ H,
                                               const float* __restrict__ a,
                                               float* __restrict__ el,
                                               float* __restrict__ er, int L) {
  const int row  = (blockIdx.x * 256 + threadIdx.x) >> 6;
  const int lane = threadIdx.x & 63;
  const float* hr = H + (size_t)row * L;
  float sl = 0.f, sr = 0.f;
  for (int f = lane; f < L; f += 64) {
    float h = hr[f];
    sl += h * a[f];
    sr += h * a[L + f];
  }
#pragma unroll
  for (int off = 32; off > 0; off >>= 1) {
    sl += __shfl_down(sl, off);
    sr += __shfl_down(sr, off);
  }
  if (lane == 0) { el[row] = sl; er[row] = sr; }
}

__global__ __launch_bounds__(256) void rowdot1(const float* __restrict__ H,
                                               const float* __restrict__ a,
                                               float* __restrict__ w, int L) {
  const int row  = (blockIdx.x * 256 + threadIdx.x) >> 6;
  const int lane = threadIdx.x & 63;
  const float* hr = H + (size_t)row * L;
  float s = 0.f;
  for (int f = lane; f < L; f += 64) s += hr[f] * a[f];
#pragma unroll
  for (int off = 32; off > 0; off >>= 1) s += __shfl_down(s, off);
  if (lane == 0) w[row] = s;
}

// ---------------------------------------------------------------------------
// Per-batch min/max of el, er -> (mn, 30/(mx-mn)) using monotonicity of leaky.
// ---------------------------------------------------------------------------
__global__ __launch_bounds__(256) void minmax_params(const float* __restrict__ el,
                                                     const float* __restrict__ er,
                                                     float2* __restrict__ params) {
  __shared__ float smnl[256], smxl[256], smnr[256], smxr[256];
  const int b = blockIdx.x, t = threadIdx.x;
  float mnl = 3.4e38f, mxl = -3.4e38f, mnr = 3.4e38f, mxr = -3.4e38f;
  for (int i = t; i < NN; i += 256) {
    float v = el[b * NN + i];
    mnl = fminf(mnl, v); mxl = fmaxf(mxl, v);
    float u = er[b * NN + i];
    mnr = fminf(mnr, u); mxr = fmaxf(mxr, u);
  }
  smnl[t] = mnl; smxl[t] = mxl; smnr[t] = mnr; smxr[t] = mxr;
  __syncthreads();
  for (int s = 128; s > 0; s >>= 1) {
    if (t < s) {
      smnl[t] = fminf(smnl[t], smnl[t + s]);
      smxl[t] = fmaxf(smxl[t], smxl[t + s]);
      smnr[t] = fminf(smnr[t], smnr[t + s]);
      smxr[t] = fmaxf(smxr[t], smxr[t + s]);
    }
    __syncthreads();
  }
  if (t == 0) {
    float mn = leakyf(smnl[0] + smnr[0]);
    float mx = leakyf(smxl[0] + smxr[0]);
    params[b] = make_float2(mn, 30.0f / (mx - mn));
  }
}

// ---------------------------------------------------------------------------
// Materialize fc2 output: fc2[b,i,j] = sigmoid(e2(b,i,j)). float4 per thread.
// ---------------------------------------------------------------------------
__global__ __launch_bounds__(256) void fc2_write(const float* __restrict__ el,
                                                 const float* __restrict__ er,
                                                 const float2* __restrict__ params,
                                                 float* __restrict__ fc2) {
  const int idx = blockIdx.x * 256 + threadIdx.x;   // [0, B*N*N/4)
  const int j  = (idx & 255) << 2;
  const int bi = idx >> 8;
  const int i  = bi & 1023;
  const int b  = bi >> 10;
  const float2 p = params[b];
  const float eli = el[b * NN + i];
  const float4 erv = *(const float4*)&er[b * NN + j];
  float4 o;
  o.x = sigm((leakyf(eli + erv.x) - p.x) * p.y - 20.0f);
  o.y = sigm((leakyf(eli + erv.y) - p.x) * p.y - 20.0f);
  o.z = sigm((leakyf(eli + erv.z) - p.x) * p.y - 20.0f);
  o.w = sigm((leakyf(eli + erv.w) - p.x) * p.y - 20.0f);
  *(float4*)&fc2[(size_t)bi * NN + j] = o;
}

// ---------------------------------------------------------------------------
// out[b,i] = leaky( sum_j att2(i,j) * w[b,j] + bg ). One wave per row.
// ---------------------------------------------------------------------------
__global__ __launch_bounds__(256) void final_out(const float* __restrict__ el,
                                                 const float* __restrict__ er,
                                                 const float2* __restrict__ params,
                                                 const float* __restrict__ w,
                                                 const float* __restrict__ bg,
                                                 float* __restrict__ out) {
  const int row  = (blockIdx.x * 256 + threadIdx.x) >> 6;  // b*N+i
  const int lane = threadIdx.x & 63;
  const int b = row >> 10;
  const float2 p = params[b];
  const float eli = el[row];
  const float* erb = er + (b << 10);
  const float* wb  = w + (b << 10);
  float s = 0.f;
  for (int j = lane; j < NN; j += 64) {
    float e = (leakyf(eli + erb[j]) - p.x) * p.y - 20.0f;
    s += wb[j] * sigm(e);
  }
#pragma unroll
  for (int off = 32; off > 0; off >>= 1) s += __shfl_down(s, off);
  if (lane == 0) out[row] = leakyf(s + bg[0]);
}

extern "C" void kernel_launch(void* const* d_in, const int* in_sizes, int n_in,
                              void* d_out, int out_size, void* d_ws, size_t ws_size,
                              hipStream_t stream) {
  (void)in_sizes; (void)n_in; (void)out_size; (void)ws_size;
  const float* x  = (const float*)d_in[0];
  // d_in[1] edge_weight: unused by the reference network
  const float* W1 = (const float*)d_in[2];
  const float* a1 = (const float*)d_in[3];
  const float* W2 = (const float*)d_in[4];
  const float* a2 = (const float*)d_in[5];
  const float* Wg = (const float*)d_in[6];
  const float* bg = (const float*)d_in[7];

  float* out = (float*)d_out;               // [B,N,1]      32768
  float* fc2 = out + 32768;                 // [B,N,N]      33554432
  float* g2  = fc2 + 33554432;              // [B,N,H2]     4194304

  // h1/g1 live inside the fc2 output region (dead before fc2 is written)
  float* h1 = fc2;                          // 8388608 floats
  float* g1 = fc2 + 8388608;                // 8388608 floats

  float* ws  = (float*)d_ws;
  float* el1 = ws;                          // 32768
  float* er1 = ws + 32768;                  // 32768
  float* el2 = ws + 65536;                  // 32768
  float* er2 = ws + 98304;                  // 32768
  float2* p1 = (float2*)(ws + 131072);      // 32 float2
  float2* p2 = (float2*)(ws + 131136);      // 32 float2
  float* wv  = ws + 131200;                 // 32768
  float* h2  = ws + 163968;                 // 4194304

  dim3 blk(256);
  // Stage 1
  gemm_plain<<<dim3(512, 4), blk, 0, stream>>>(x, W1, h1, FIN, HH1);
  rowdot2<<<8192, blk, 0, stream>>>(h1, a1, el1, er1, HH1);
  minmax_params<<<32, blk, 0, stream>>>(el1, er1, p1);
  gemm_att<<<dim3(16, 4, 32), blk, 0, stream>>>(el1, er1, p1, h1, g1, HH1, 1);
  // Stage 2
  gemm_plain<<<dim3(512, 2), blk, 0, stream>>>(g1, W2, h2, HH1, HH2);
  rowdot2<<<8192, blk, 0, stream>>>(h2, a2, el2, er2, HH2);
  minmax_params<<<32, blk, 0, stream>>>(el2, er2, p2);
  fc2_write<<<32768, blk, 0, stream>>>(el2, er2, p2, fc2);   // kills h1/g1 (dead)
  gemm_att<<<dim3(16, 2, 32), blk, 0, stream>>>(el2, er2, p2, h2, g2, HH2, 0);
  // Stage 3: z = fc2 @ (g2 @ Wg) + bg, att recomputed on the fly
  rowdot1<<<8192, blk, 0, stream>>>(g2, Wg, wv, HH2);
  final_out<<<8192, blk, 0, stream>>>(el2, er2, p2, wv, bg, out);
}

// Round 3
// 527.901 us; speedup vs baseline: 1.6983x; 1.6983x over previous
//
#include <hip/hip_runtime.h>

#define NN 1024
#define FIN 512
#define HH1 256
#define HH2 128
#define MTOT 32768   // B*N total rows

using bf16x8 = __attribute__((ext_vector_type(8))) short;
using f32x4  = __attribute__((ext_vector_type(4))) float;

__device__ __forceinline__ float leakyf(float x) { return fmaxf(x, 0.01f * x); }
__device__ __forceinline__ float sigm(float x) { return 1.0f / (1.0f + __expf(-x)); }
__device__ __forceinline__ float eluf(float x) { return x > 0.0f ? x : __expf(x) - 1.0f; }
__device__ __forceinline__ unsigned short f2bf(float f) {   // RNE fp32->bf16
  union { float f; unsigned u; } v; v.f = f;
  unsigned r = v.u + 0x7FFFu + ((v.u >> 16) & 1u);
  return (unsigned short)(r >> 16);
}
__device__ __forceinline__ float bf2f(unsigned short u) {
  union { unsigned u; float f; } v; v.u = ((unsigned)u) << 16; return v.f;
}
// split x -> hi + lo (two bf16, ~16 mantissa bits total; residual exact in fp32)
__device__ __forceinline__ void split2(float x, unsigned short& h, unsigned short& l) {
  h = f2bf(x);
  l = f2bf(x - bf2f(h));
}

// ---------------------------------------------------------------------------
// fp32 -> (hi, lo) bf16 pair, 4 elements/thread
// ---------------------------------------------------------------------------
__global__ __launch_bounds__(256) void cvt_split(const float* __restrict__ in,
                                                 unsigned short* __restrict__ hi,
                                                 unsigned short* __restrict__ lo, int n) {
  int i = (blockIdx.x * 256 + threadIdx.x) * 4;
  if (i >= n) return;
  float4 a = *(const float4*)&in[i];
  ushort4 h, l;
  split2(a.x, h.x, l.x); split2(a.y, h.y, l.y);
  split2(a.z, h.z, l.z); split2(a.w, h.w, l.w);
  *(ushort4*)&hi[i] = h;
  *(ushort4*)&lo[i] = l;
}

// W[K][N] fp32 -> WT[N][K] (hi, lo) bf16. K = 1<<kshift. grid*256 == K*N.
__global__ __launch_bounds__(256) void transpose_w_split(const float* __restrict__ W,
                                                         unsigned short* __restrict__ WThi,
                                                         unsigned short* __restrict__ WTlo,
                                                         int Nc, int kshift) {
  int idx = blockIdx.x * 256 + threadIdx.x;
  int k = idx & ((1 << kshift) - 1);
  int n = idx >> kshift;
  unsigned short h, l;
  split2(W[(size_t)k * Nc + n], h, l);
  WThi[idx] = h; WTlo[idx] = l;
}

// ---------------------------------------------------------------------------
// Split-bf16 MFMA GEMM: C = A @ B, A=[M,K] (hi,lo), B given transposed
// BT=[Nc,K] (hi,lo). C ~= Ah Bh + Ah Bl + Al Bh (fp32-quality).
// Block 128x128, 4 waves 2x2, wave tile 64x64 (4x4 frags of 16x16x32).
// Writes C row-major split (Chi,Clo, ld=Nc) and C^T split (CThi,CTlo, ld=MTOT).
// ---------------------------------------------------------------------------
__global__ __launch_bounds__(256) void gemm_split(const unsigned short* __restrict__ Ahi,
                                                  const unsigned short* __restrict__ Alo,
                                                  const unsigned short* __restrict__ BThi,
                                                  const unsigned short* __restrict__ BTlo,
                                                  unsigned short* __restrict__ Chi,
                                                  unsigned short* __restrict__ Clo,
                                                  unsigned short* __restrict__ CThi,
                                                  unsigned short* __restrict__ CTlo,
                                                  int K, int Nc) {
  __shared__ unsigned short Ah[128 * 40];   // [m][k], stride 40 (pad 8)
  __shared__ unsigned short Al[128 * 40];
  __shared__ unsigned short Bh[128 * 40];   // [n][k]
  __shared__ unsigned short Bl[128 * 40];
  const int t    = threadIdx.x;
  const int lane = t & 63;
  const int wid  = t >> 6;
  const int wm   = (wid & 1) * 64;
  const int wn   = (wid >> 1) * 64;
  const int ln   = lane & 15;
  const int quad = lane >> 4;
  const int m0 = blockIdx.x * 128;
  const int n0 = blockIdx.y * 128;
  const int r  = t >> 1;
  const int hh = (t & 1) * 16;
  const unsigned short* aph = Ahi  + (size_t)(m0 + r) * K + hh;
  const unsigned short* apl = Alo  + (size_t)(m0 + r) * K + hh;
  const unsigned short* bph = BThi + (size_t)(n0 + r) * K + hh;
  const unsigned short* bpl = BTlo + (size_t)(n0 + r) * K + hh;
  f32x4 acc[4][4];
#pragma unroll
  for (int mi = 0; mi < 4; ++mi)
#pragma unroll
    for (int ni = 0; ni < 4; ++ni) acc[mi][ni] = (f32x4){0.f, 0.f, 0.f, 0.f};

  for (int k0 = 0; k0 < K; k0 += 32) {
    uint4 vah0 = *(const uint4*)(aph + k0);
    uint4 vah1 = *(const uint4*)(aph + k0 + 8);
    uint4 val0 = *(const uint4*)(apl + k0);
    uint4 val1 = *(const uint4*)(apl + k0 + 8);
    uint4 vbh0 = *(const uint4*)(bph + k0);
    uint4 vbh1 = *(const uint4*)(bph + k0 + 8);
    uint4 vbl0 = *(const uint4*)(bpl + k0);
    uint4 vbl1 = *(const uint4*)(bpl + k0 + 8);
    __syncthreads();
    *(uint4*)&Ah[r * 40 + hh]     = vah0;
    *(uint4*)&Ah[r * 40 + hh + 8] = vah1;
    *(uint4*)&Al[r * 40 + hh]     = val0;
    *(uint4*)&Al[r * 40 + hh + 8] = val1;
    *(uint4*)&Bh[r * 40 + hh]     = vbh0;
    *(uint4*)&Bh[r * 40 + hh + 8] = vbh1;
    *(uint4*)&Bl[r * 40 + hh]     = vbl0;
    *(uint4*)&Bl[r * 40 + hh + 8] = vbl1;
    __syncthreads();
    bf16x8 ah[4], al[4], bh[4], bl[4];
#pragma unroll
    for (int i = 0; i < 4; ++i) {
      const int ao = (wm + i * 16 + ln) * 40 + quad * 8;
      const int bo = (wn + i * 16 + ln) * 40 + quad * 8;
      ah[i] = *(const bf16x8*)&Ah[ao];
      al[i] = *(const bf16x8*)&Al[ao];
      bh[i] = *(const bf16x8*)&Bh[bo];
      bl[i] = *(const bf16x8*)&Bl[bo];
    }
#pragma unroll
    for (int mi = 0; mi < 4; ++mi)
#pragma unroll
      for (int ni = 0; ni < 4; ++ni) {
        acc[mi][ni] = __builtin_amdgcn_mfma_f32_16x16x32_bf16(ah[mi], bh[ni], acc[mi][ni], 0, 0, 0);
        acc[mi][ni] = __builtin_amdgcn_mfma_f32_16x16x32_bf16(ah[mi], bl[ni], acc[mi][ni], 0, 0, 0);
        acc[mi][ni] = __builtin_amdgcn_mfma_f32_16x16x32_bf16(al[mi], bh[ni], acc[mi][ni], 0, 0, 0);
      }
  }
#pragma unroll
  for (int mi = 0; mi < 4; ++mi) {
    const int mr = m0 + wm + mi * 16 + quad * 4;
#pragma unroll
    for (int ni = 0; ni < 4; ++ni) {
      const int c = n0 + wn + ni * 16 + ln;
      ushort4 ph, pl;
      split2(acc[mi][ni][0], ph.x, pl.x);
      split2(acc[mi][ni][1], ph.y, pl.y);
      split2(acc[mi][ni][2], ph.z, pl.z);
      split2(acc[mi][ni][3], ph.w, pl.w);
      Chi[(size_t)(mr + 0) * Nc + c] = ph.x;
      Chi[(size_t)(mr + 1) * Nc + c] = ph.y;
      Chi[(size_t)(mr + 2) * Nc + c] = ph.z;
      Chi[(size_t)(mr + 3) * Nc + c] = ph.w;
      Clo[(size_t)(mr + 0) * Nc + c] = pl.x;
      Clo[(size_t)(mr + 1) * Nc + c] = pl.y;
      Clo[(size_t)(mr + 2) * Nc + c] = pl.z;
      Clo[(size_t)(mr + 3) * Nc + c] = pl.w;
      *(ushort4*)&CThi[(size_t)c * MTOT + mr] = ph;
      *(ushort4*)&CTlo[(size_t)c * MTOT + mr] = pl;
    }
  }
}

// ---------------------------------------------------------------------------
// Split attention MFMA GEMM (batched over blockIdx.z):
// C[i,f] = sum_j att(i,j) * h[j,f]; att synthesized fp32 then split to hi/lo.
// hT split: [Fo][MTOT]. Stage1 (g1hi!=0): elu + split bf16 out. Else fp32 out.
// ---------------------------------------------------------------------------
__global__ __launch_bounds__(256) void gemm_att_split(const float* __restrict__ el,
                                                      const float* __restrict__ er,
                                                      const float2* __restrict__ params,
                                                      const unsigned short* __restrict__ hThi,
                                                      const unsigned short* __restrict__ hTlo,
                                                      unsigned short* __restrict__ g1hi,
                                                      unsigned short* __restrict__ g1lo,
                                                      float* __restrict__ outf,
                                                      int Nc) {
  __shared__ unsigned short Ah[128 * 40];
  __shared__ unsigned short Al[128 * 40];
  __shared__ unsigned short Bh[128 * 40];
  __shared__ unsigned short Bl[128 * 40];
  __shared__ float ers[NN];
  const int b    = blockIdx.z;
  const int t    = threadIdx.x;
  const int lane = t & 63;
  const int wid  = t >> 6;
  const int wm   = (wid & 1) * 64;
  const int wn   = (wid >> 1) * 64;
  const int ln   = lane & 15;
  const int quad = lane >> 4;
  const int m0 = blockIdx.x * 128;
  const int n0 = blockIdx.y * 128;
  const float2 p = params[b];
  const float pinv = p.y;
  const float pc   = -p.x * p.y - 20.0f;
  *(float4*)&ers[t * 4] = *(const float4*)&er[b * NN + t * 4];
  const int r  = t >> 1;
  const int hh = (t & 1) * 16;
  const float elv = el[b * NN + m0 + r];
  const unsigned short* bph = hThi + (size_t)(n0 + r) * MTOT + b * NN + hh;
  const unsigned short* bpl = hTlo + (size_t)(n0 + r) * MTOT + b * NN + hh;
  f32x4 acc[4][4];
#pragma unroll
  for (int mi = 0; mi < 4; ++mi)
#pragma unroll
    for (int ni = 0; ni < 4; ++ni) acc[mi][ni] = (f32x4){0.f, 0.f, 0.f, 0.f};
  __syncthreads();   // ers visible

  for (int k0 = 0; k0 < NN; k0 += 32) {
    uint4 vbh0 = *(const uint4*)(bph + k0);
    uint4 vbh1 = *(const uint4*)(bph + k0 + 8);
    uint4 vbl0 = *(const uint4*)(bpl + k0);
    uint4 vbl1 = *(const uint4*)(bpl + k0 + 8);
    ushort4 sh[4], sl[4];
#pragma unroll
    for (int q = 0; q < 4; ++q) {
#pragma unroll
      for (int j = 0; j < 4; ++j) {
        float x = elv + ers[k0 + hh + q * 4 + j];
        x = fmaxf(x, 0.01f * x);
        float s = sigm(fmaf(x, pinv, pc));
        split2(s, (&sh[q].x)[j], (&sl[q].x)[j]);
      }
    }
    __syncthreads();
#pragma unroll
    for (int q = 0; q < 4; ++q) {
      *(ushort4*)&Ah[r * 40 + hh + q * 4] = sh[q];
      *(ushort4*)&Al[r * 40 + hh + q * 4] = sl[q];
    }
    *(uint4*)&Bh[r * 40 + hh]     = vbh0;
    *(uint4*)&Bh[r * 40 + hh + 8] = vbh1;
    *(uint4*)&Bl[r * 40 + hh]     = vbl0;
    *(uint4*)&Bl[r * 40 + hh + 8] = vbl1;
    __syncthreads();
    bf16x8 ah[4], al[4], bh[4], bl[4];
#pragma unroll
    for (int i = 0; i < 4; ++i) {
      const int ao = (wm + i * 16 + ln) * 40 + quad * 8;
      const int bo = (wn + i * 16 + ln) * 40 + quad * 8;
      ah[i] = *(const bf16x8*)&Ah[ao];
      al[i] = *(const bf16x8*)&Al[ao];
      bh[i] = *(const bf16x8*)&Bh[bo];
      bl[i] = *(const bf16x8*)&Bl[bo];
    }
#pragma unroll
    for (int mi = 0; mi < 4; ++mi)
#pragma unroll
      for (int ni = 0; ni < 4; ++ni) {
        acc[mi][ni] = __builtin_amdgcn_mfma_f32_16x16x32_bf16(ah[mi], bh[ni], acc[mi][ni], 0, 0, 0);
        acc[mi][ni] = __builtin_amdgcn_mfma_f32_16x16x32_bf16(ah[mi], bl[ni], acc[mi][ni], 0, 0, 0);
        acc[mi][ni] = __builtin_amdgcn_mfma_f32_16x16x32_bf16(al[mi], bh[ni], acc[mi][ni], 0, 0, 0);
      }
  }
#pragma unroll
  for (int mi = 0; mi < 4; ++mi) {
    const int mr = m0 + wm + mi * 16 + quad * 4;   // row within batch
#pragma unroll
    for (int ni = 0; ni < 4; ++ni) {
      const int c = n0 + wn + ni * 16 + ln;
      if (g1hi) {
#pragma unroll
        for (int rr = 0; rr < 4; ++rr) {
          float v = eluf(acc[mi][ni][rr]);
          unsigned short h, l;
          split2(v, h, l);
          g1hi[(size_t)(b * NN + mr + rr) * Nc + c] = h;
          g1lo[(size_t)(b * NN + mr + rr) * Nc + c] = l;
        }
      } else {
#pragma unroll
        for (int rr = 0; rr < 4; ++rr)
          outf[((size_t)b * NN + mr + rr) * Nc + c] = acc[mi][ni][rr];
      }
    }
  }
}

// ---------------------------------------------------------------------------
// el/er dot products from split bf16 H. One wave per row.
// ---------------------------------------------------------------------------
__global__ __launch_bounds__(256) void rowdot2_split(const unsigned short* __restrict__ Hhi,
                                                     const unsigned short* __restrict__ Hlo,
                                                     const float* __restrict__ a,
                                                     float* __restrict__ el,
                                                     float* __restrict__ er, int L) {
  const int row  = (blockIdx.x * 256 + threadIdx.x) >> 6;
  const int lane = threadIdx.x & 63;
  const unsigned short* hrh = Hhi + (size_t)row * L;
  const unsigned short* hrl = Hlo + (size_t)row * L;
  float sl = 0.f, sr = 0.f;
  for (int f = lane * 4; f < L; f += 256) {
    ushort4 hv = *(const ushort4*)&hrh[f];
    ushort4 lv = *(const ushort4*)&hrl[f];
    float4 av  = *(const float4*)&a[f];
    float4 aw  = *(const float4*)&a[L + f];
    float h0 = bf2f(hv.x) + bf2f(lv.x);
    float h1 = bf2f(hv.y) + bf2f(lv.y);
    float h2 = bf2f(hv.z) + bf2f(lv.z);
    float h3 = bf2f(hv.w) + bf2f(lv.w);
    sl += h0 * av.x + h1 * av.y + h2 * av.z + h3 * av.w;
    sr += h0 * aw.x + h1 * aw.y + h2 * aw.z + h3 * aw.w;
  }
#pragma unroll
  for (int off = 32; off > 0; off >>= 1) {
    sl += __shfl_down(sl, off);
    sr += __shfl_down(sr, off);
  }
  if (lane == 0) { el[row] = sl; er[row] = sr; }
}

__global__ __launch_bounds__(256) void rowdot1(const float* __restrict__ H,
                                               const float* __restrict__ a,
                                               float* __restrict__ w, int L) {
  const int row  = (blockIdx.x * 256 + threadIdx.x) >> 6;
  const int lane = threadIdx.x & 63;
  const float* hr = H + (size_t)row * L;
  float s = 0.f;
  for (int f = lane; f < L; f += 64) s += hr[f] * a[f];
#pragma unroll
  for (int off = 32; off > 0; off >>= 1) s += __shfl_down(s, off);
  if (lane == 0) w[row] = s;
}

// Per-batch min/max of el, er -> (mn, 30/(mx-mn)); leaky is monotone.
__global__ __launch_bounds__(256) void minmax_params(const float* __restrict__ el,
                                                     const float* __restrict__ er,
                                                     float2* __restrict__ params) {
  __shared__ float smnl[256], smxl[256], smnr[256], smxr[256];
  const int b = blockIdx.x, t = threadIdx.x;
  float mnl = 3.4e38f, mxl = -3.4e38f, mnr = 3.4e38f, mxr = -3.4e38f;
  for (int i = t; i < NN; i += 256) {
    float v = el[b * NN + i];
    mnl = fminf(mnl, v); mxl = fmaxf(mxl, v);
    float u = er[b * NN + i];
    mnr = fminf(mnr, u); mxr = fmaxf(mxr, u);
  }
  smnl[t] = mnl; smxl[t] = mxl; smnr[t] = mnr; smxr[t] = mxr;
  __syncthreads();
  for (int s = 128; s > 0; s >>= 1) {
    if (t < s) {
      smnl[t] = fminf(smnl[t], smnl[t + s]);
      smxl[t] = fmaxf(smxl[t], smxl[t + s]);
      smnr[t] = fminf(smnr[t], smnr[t + s]);
      smxr[t] = fmaxf(smxr[t], smxr[t + s]);
    }
    __syncthreads();
  }
  if (t == 0) {
    float mn = leakyf(smnl[0] + smnr[0]);
    float mx = leakyf(smxl[0] + smxr[0]);
    params[b] = make_float2(mn, 30.0f / (mx - mn));
  }
}

// ---------------------------------------------------------------------------
// Fused: fc2[b,i,j] = att2(i,j) (fp32) AND out[b,i] = leaky(sum_j att*w + bg).
// One wave per row i; lanes cover 4 consecutive j each (coalesced float4).
// ---------------------------------------------------------------------------
__global__ __launch_bounds__(256) void final_out_fc2(const float* __restrict__ el,
                                                     const float* __restrict__ er,
                                                     const float2* __restrict__ params,
                                                     const float* __restrict__ w,
                                                     const float* __restrict__ bg,
                                                     float* __restrict__ fc2,
                                                     float* __restrict__ out) {
  const int row  = (blockIdx.x * 256 + threadIdx.x) >> 6;  // b*N+i
  const int lane = threadIdx.x & 63;
  const int b = row >> 10;
  const float2 p = params[b];
  const float pinv = p.y;
  const float pc   = -p.x * p.y - 20.0f;
  const float eli = el[row];
  const float* erb = er + (b << 10);
  const float* wb  = w + (b << 10);
  float* fcrow = fc2 + (size_t)row * NN;
  float s = 0.f;
  for (int j = lane * 4; j < NN; j += 256) {
    float4 e4 = *(const float4*)&erb[j];
    float4 w4 = *(const float4*)&wb[j];
    float4 a;
    a.x = sigm(fmaf(leakyf(eli + e4.x), pinv, pc));
    a.y = sigm(fmaf(leakyf(eli + e4.y), pinv, pc));
    a.z = sigm(fmaf(leakyf(eli + e4.z), pinv, pc));
    a.w = sigm(fmaf(leakyf(eli + e4.w), pinv, pc));
    s += w4.x * a.x + w4.y * a.y + w4.z * a.z + w4.w * a.w;
    *(float4*)&fcrow[j] = a;
  }
#pragma unroll
  for (int off = 32; off > 0; off >>= 1) s += __shfl_down(s, off);
  if (lane == 0) out[row] = leakyf(s + bg[0]);
}

extern "C" void kernel_launch(void* const* d_in, const int* in_sizes, int n_in,
                              void* d_out, int out_size, void* d_ws, size_t ws_size,
                              hipStream_t stream) {
  (void)in_sizes; (void)n_in; (void)out_size; (void)ws_size;
  const float* x  = (const float*)d_in[0];
  const float* W1 = (const float*)d_in[2];
  const float* a1 = (const float*)d_in[3];
  const float* W2 = (const float*)d_in[4];
  const float* a2 = (const float*)d_in[5];
  const float* Wg = (const float*)d_in[6];
  const float* bg = (const float*)d_in[7];

  float* out = (float*)d_out;               // [B,N,1]   32768
  float* fc2 = out + 32768;                 // [B,N,N]   33554432
  float* g2  = fc2 + 33554432;              // [B,N,H2]  4194304

  // Scratch inside the fc2 region (fc2 is written LAST, by final_out_fc2).
  // Liveness: x* dead after gemm1; h1b dead after rowdot; h1T dead after att1;
  // g1 (reuses x region) dead after gemm2; h2* dead after att2/rowdot.
  unsigned short* xhi   = (unsigned short*)fc2;                 // [32768,512]
  unsigned short* xlo   = (unsigned short*)(fc2 + 8388608);
  unsigned short* h1bhi = (unsigned short*)(fc2 + 16777216);    // [32768,256]
  unsigned short* h1blo = (unsigned short*)(fc2 + 20971520);
  unsigned short* h1Thi = (unsigned short*)(fc2 + 25165824);    // [256,32768]
  unsigned short* h1Tlo = (unsigned short*)(fc2 + 29360128);
  unsigned short* g1hi  = (unsigned short*)fc2;                 // [32768,256]
  unsigned short* g1lo  = (unsigned short*)(fc2 + 4194304);
  unsigned short* h2bhi = (unsigned short*)(fc2 + 8388608);     // [32768,128]
  unsigned short* h2blo = (unsigned short*)(fc2 + 10485760);
  unsigned short* h2Thi = (unsigned short*)(fc2 + 12582912);    // [128,32768]
  unsigned short* h2Tlo = (unsigned short*)(fc2 + 14680064);

  float* wsf = (float*)d_ws;
  float* el1 = wsf;                          // 32768
  float* er1 = wsf + 32768;
  float* el2 = wsf + 65536;
  float* er2 = wsf + 98304;
  float* wv  = wsf + 131072;                 // 32768
  float2* p1 = (float2*)(wsf + 163840);      // 32 float2
  float2* p2 = (float2*)(wsf + 163904);
  unsigned short* W1Thi = (unsigned short*)(wsf + 163968);   // [256,512]
  unsigned short* W1Tlo = (unsigned short*)(wsf + 229504);
  unsigned short* W2Thi = (unsigned short*)(wsf + 295040);   // [128,256]
  unsigned short* W2Tlo = (unsigned short*)(wsf + 311424);

  dim3 blk(256);
  // Precision prep
  cvt_split<<<16384, blk, 0, stream>>>(x, xhi, xlo, 32 * NN * FIN);
  transpose_w_split<<<512, blk, 0, stream>>>(W1, W1Thi, W1Tlo, HH1, 9);
  transpose_w_split<<<128, blk, 0, stream>>>(W2, W2Thi, W2Tlo, HH2, 8);
  // Stage 1
  gemm_split<<<dim3(256, 2), blk, 0, stream>>>(xhi, xlo, W1Thi, W1Tlo,
                                               h1bhi, h1blo, h1Thi, h1Tlo, FIN, HH1);
  rowdot2_split<<<8192, blk, 0, stream>>>(h1bhi, h1blo, a1, el1, er1, HH1);
  minmax_params<<<32, blk, 0, stream>>>(el1, er1, p1);
  gemm_att_split<<<dim3(8, 2, 32), blk, 0, stream>>>(el1, er1, p1, h1Thi, h1Tlo,
                                                     g1hi, g1lo, nullptr, HH1);
  // Stage 2
  gemm_split<<<dim3(256, 1), blk, 0, stream>>>(g1hi, g1lo, W2Thi, W2Tlo,
                                               h2bhi, h2blo, h2Thi, h2Tlo, HH1, HH2);
  rowdot2_split<<<8192, blk, 0, stream>>>(h2bhi, h2blo, a2, el2, er2, HH2);
  minmax_params<<<32, blk, 0, stream>>>(el2, er2, p2);
  gemm_att_split<<<dim3(8, 1, 32), blk, 0, stream>>>(el2, er2, p2, h2Thi, h2Tlo,
                                                     nullptr, nullptr, g2, HH2);
  // Stage 3: z = fc2 @ (g2 @ Wg) + bg; fc2 write fused into final kernel.
  rowdot1<<<8192, blk, 0, stream>>>(g2, Wg, wv, HH2);
  final_out_fc2<<<8192, blk, 0, stream>>>(el2, er2, p2, wv, bg, fc2, out);
}

// Round 4
// 513.259 us; speedup vs baseline: 1.7468x; 1.0285x over previous
//
#include <hip/hip_runtime.h>

#define NN 1024
#define FIN 512
#define HH1 256
#define HH2 128
#define MTOT 32768   // B*N total rows

typedef unsigned short ushort_t;
using bf16x8 = __attribute__((ext_vector_type(8))) short;
using f32x4  = __attribute__((ext_vector_type(4))) float;

__device__ __forceinline__ float leakyf(float x) { return fmaxf(x, 0.01f * x); }
__device__ __forceinline__ float eluf(float x) { return x > 0.0f ? x : __expf(x) - 1.0f; }
// pack the high halves of two fp32 bit patterns: [u1.hi : u0.hi]
__device__ __forceinline__ unsigned pack_hi(unsigned u0, unsigned u1) {
  return __builtin_amdgcn_perm(u1, u0, 0x07060302u);
}
// trunc-split two fp32 -> bf16 hi pair + bf16 lo pair (lo compensates hi trunc)
__device__ __forceinline__ void split_pack2(float f0, float f1, unsigned& hp, unsigned& lp) {
  unsigned u0 = __float_as_uint(f0), u1 = __float_as_uint(f1);
  hp = pack_hi(u0, u1);
  float l0 = f0 - __uint_as_float(u0 & 0xFFFF0000u);
  float l1 = f1 - __uint_as_float(u1 & 0xFFFF0000u);
  lp = pack_hi(__float_as_uint(l0), __float_as_uint(l1));
}
// RNE-round two fp32 to bf16 and pack
__device__ __forceinline__ unsigned pack_rne(float f0, float f1) {
  unsigned u0 = __float_as_uint(f0); u0 += 0x7FFFu + ((u0 >> 16) & 1u);
  unsigned u1 = __float_as_uint(f1); u1 += 0x7FFFu + ((u1 >> 16) & 1u);
  return pack_hi(u0, u1);
}

// ---------------------------------------------------------------------------
// W[K][N] fp32 -> WT[N][K] trunc-split bf16. K = 1<<kshift.
// ---------------------------------------------------------------------------
__global__ __launch_bounds__(256) void transpose_w_split(const float* __restrict__ W,
                                                         ushort_t* __restrict__ WThi,
                                                         ushort_t* __restrict__ WTlo,
                                                         int Nc, int kshift) {
  int idx = blockIdx.x * 256 + threadIdx.x;
  int k = idx & ((1 << kshift) - 1);
  int n = idx >> kshift;
  float f = W[(size_t)k * Nc + n];
  unsigned u = __float_as_uint(f);
  WThi[idx] = (ushort_t)(u >> 16);
  float lo = f - __uint_as_float(u & 0xFFFF0000u);
  WTlo[idx] = (ushort_t)(__float_as_uint(lo) >> 16);
}

// ---------------------------------------------------------------------------
// Producer GEMM, full split precision (3 MFMA): C = A(fp32)[M,K] @ B, with
// B transposed split BT[NC][K]. In-kernel trunc-split of A. Block tile
// 64 x NC (y=1: each block sees full output rows). Outputs:
//   CT split [NC][MTOT]  (B-operand for the attention GEMM)
//   el/er row dots vs avec[0:NC]/avec[NC:2NC] from the fp32 accumulators,
//   reduced in-wave and atomicAdd'ed (el/er pre-zeroed).
// ---------------------------------------------------------------------------
template<int NC>
__global__ __launch_bounds__(256) void gemm_asplit(const float* __restrict__ A,
                                                   const ushort_t* __restrict__ BThi,
                                                   const ushort_t* __restrict__ BTlo,
                                                   const float* __restrict__ avec,
                                                   ushort_t* __restrict__ CThi,
                                                   ushort_t* __restrict__ CTlo,
                                                   float* __restrict__ el,
                                                   float* __restrict__ er, int K) {
  constexpr int NFR = NC / 32;   // n-frags per wave (wave tile 32 x NC/2)
  constexpr int NB  = NC / 64;   // 16B B-chunks per thread per buffer
  __shared__ ushort_t Ah[64 * 40], Al[64 * 40];
  __shared__ ushort_t Bh[NC * 40], Bl[NC * 40];
  __shared__ float aL[NC], aR[NC];
  const int t = threadIdx.x, lane = t & 63, wid = t >> 6;
  const int wm = (wid & 1) * 32, wn = (wid >> 1) * (NC / 2);
  const int ln = lane & 15, quad = lane >> 4;
  const int m0 = blockIdx.x * 64;
  if (t < NC) { aL[t] = avec[t]; aR[t] = avec[NC + t]; }
  const int ra = t >> 2, ka = (t & 3) * 8;
  const float* ap = A + (size_t)(m0 + ra) * K + ka;
  const int brow = (t >> 2);            // + i*64 per chunk
  const int bko  = (t & 3) * 8;
  f32x4 acc[2][NFR];
#pragma unroll
  for (int mi = 0; mi < 2; ++mi)
#pragma unroll
    for (int ni = 0; ni < NFR; ++ni) acc[mi][ni] = (f32x4){0.f, 0.f, 0.f, 0.f};

  for (int k0 = 0; k0 < K; k0 += 32) {
    float4 fa0 = *(const float4*)(ap + k0);
    float4 fa1 = *(const float4*)(ap + k0 + 4);
    uint4 vbh[NB], vbl[NB];
#pragma unroll
    for (int i = 0; i < NB; ++i) {
      size_t off = (size_t)(brow + i * 64) * K + k0 + bko;
      vbh[i] = *(const uint4*)&BThi[off];
      vbl[i] = *(const uint4*)&BTlo[off];
    }
    uint4 ah4, al4;
    split_pack2(fa0.x, fa0.y, ah4.x, al4.x);
    split_pack2(fa0.z, fa0.w, ah4.y, al4.y);
    split_pack2(fa1.x, fa1.y, ah4.z, al4.z);
    split_pack2(fa1.z, fa1.w, ah4.w, al4.w);
    __syncthreads();
    *(uint4*)&Ah[ra * 40 + ka] = ah4;
    *(uint4*)&Al[ra * 40 + ka] = al4;
#pragma unroll
    for (int i = 0; i < NB; ++i) {
      *(uint4*)&Bh[(brow + i * 64) * 40 + bko] = vbh[i];
      *(uint4*)&Bl[(brow + i * 64) * 40 + bko] = vbl[i];
    }
    __syncthreads();
    bf16x8 ahf[2], alf[2], bhf[NFR], blf[NFR];
#pragma unroll
    for (int i = 0; i < 2; ++i) {
      const int ao = (wm + i * 16 + ln) * 40 + quad * 8;
      ahf[i] = *(const bf16x8*)&Ah[ao];
      alf[i] = *(const bf16x8*)&Al[ao];
    }
#pragma unroll
    for (int i = 0; i < NFR; ++i) {
      const int bo = (wn + i * 16 + ln) * 40 + quad * 8;
      bhf[i] = *(const bf16x8*)&Bh[bo];
      blf[i] = *(const bf16x8*)&Bl[bo];
    }
#pragma unroll
    for (int mi = 0; mi < 2; ++mi)
#pragma unroll
      for (int ni = 0; ni < NFR; ++ni) {
        acc[mi][ni] = __builtin_amdgcn_mfma_f32_16x16x32_bf16(ahf[mi], bhf[ni], acc[mi][ni], 0, 0, 0);
        acc[mi][ni] = __builtin_amdgcn_mfma_f32_16x16x32_bf16(ahf[mi], blf[ni], acc[mi][ni], 0, 0, 0);
        acc[mi][ni] = __builtin_amdgcn_mfma_f32_16x16x32_bf16(alf[mi], bhf[ni], acc[mi][ni], 0, 0, 0);
      }
  }
#pragma unroll
  for (int mi = 0; mi < 2; ++mi) {
    const int mr = m0 + wm + mi * 16 + quad * 4;
#pragma unroll
    for (int ni = 0; ni < NFR; ++ni) {
      const int c = wn + ni * 16 + ln;
      unsigned h01, l01, h23, l23;
      split_pack2(acc[mi][ni][0], acc[mi][ni][1], h01, l01);
      split_pack2(acc[mi][ni][2], acc[mi][ni][3], h23, l23);
      *(uint2*)&CThi[(size_t)c * MTOT + mr] = make_uint2(h01, h23);
      *(uint2*)&CTlo[(size_t)c * MTOT + mr] = make_uint2(l01, l23);
    }
#pragma unroll
    for (int rr = 0; rr < 4; ++rr) {
      float vel = 0.f, ver = 0.f;
#pragma unroll
      for (int ni = 0; ni < NFR; ++ni) {
        const int c = wn + ni * 16 + ln;
        vel = fmaf(acc[mi][ni][rr], aL[c], vel);
        ver = fmaf(acc[mi][ni][rr], aR[c], ver);
      }
#pragma unroll
      for (int m = 1; m < 16; m <<= 1) {
        vel += __shfl_xor(vel, m);
        ver += __shfl_xor(ver, m);
      }
      if (ln == 0) {
        atomicAdd(&el[mr + rr], vel);
        atomicAdd(&er[mr + rr], ver);
      }
    }
  }
}

// Per-batch min/max of el, er -> (mn, 30/(mx-mn)); leaky is monotone.
__global__ __launch_bounds__(256) void minmax_params(const float* __restrict__ el,
                                                     const float* __restrict__ er,
                                                     float2* __restrict__ params) {
  __shared__ float smnl[256], smxl[256], smnr[256], smxr[256];
  const int b = blockIdx.x, t = threadIdx.x;
  float mnl = 3.4e38f, mxl = -3.4e38f, mnr = 3.4e38f, mxr = -3.4e38f;
  for (int i = t; i < NN; i += 256) {
    float v = el[b * NN + i];
    mnl = fminf(mnl, v); mxl = fmaxf(mxl, v);
    float u = er[b * NN + i];
    mnr = fminf(mnr, u); mxr = fmaxf(mxr, u);
  }
  smnl[t] = mnl; smxl[t] = mxl; smnr[t] = mnr; smxr[t] = mxr;
  __syncthreads();
  for (int s = 128; s > 0; s >>= 1) {
    if (t < s) {
      smnl[t] = fminf(smnl[t], smnl[t + s]);
      smxl[t] = fmaxf(smxl[t], smxl[t + s]);
      smnr[t] = fminf(smnr[t], smnr[t + s]);
      smxr[t] = fmaxf(smxr[t], smxr[t + s]);
    }
    __syncthreads();
  }
  if (t == 0) {
    float mn = leakyf(smnl[0] + smnr[0]);
    float mx = leakyf(smxl[0] + smxr[0]);
    params[b] = make_float2(mn, 30.0f / (mx - mn));
  }
}

// ---------------------------------------------------------------------------
// Attention MFMA GEMM: C[i,f] = sum_j att(i,j)*h[j,f]. att synthesized fp32,
// RNE bf16 hi-only A-operand; h split B-operand (2 MFMA). Block 64 x 128.
// doElu: stage-1 epilogue. wg!=null: fuse wv[row] = sum_f C[row,f]*wg[f]
// (atomicAdd; requires gridDim.y == 1).
// ---------------------------------------------------------------------------
__global__ __launch_bounds__(256) void gemm_att2(const float* __restrict__ el,
                                                 const float* __restrict__ er,
                                                 const float2* __restrict__ params,
                                                 const ushort_t* __restrict__ hThi,
                                                 const ushort_t* __restrict__ hTlo,
                                                 float* __restrict__ C,
                                                 const float* __restrict__ wg,
                                                 float* __restrict__ wv,
                                                 int Nc, int doElu) {
  __shared__ ushort_t Ah[64 * 40];
  __shared__ ushort_t Bh[128 * 40], Bl[128 * 40];
  __shared__ float ers[NN];
  __shared__ float wls[128];
  const int b = blockIdx.z, t = threadIdx.x, lane = t & 63, wid = t >> 6;
  const int wm = (wid & 1) * 32, wn = (wid >> 1) * 64;
  const int ln = lane & 15, quad = lane >> 4;
  const int m0 = blockIdx.x * 64, n0 = blockIdx.y * 128;
  const float2 p = params[b];
  const float npinv = -p.y;                  // q = exp(-e_s)
  const float npc   = p.x * p.y + 20.0f;
  *(float4*)&ers[t * 4] = *(const float4*)&er[b * NN + t * 4];
  if (wg && t < 128) wls[t] = wg[t];
  const int ra = t >> 2, ka = (t & 3) * 8;
  const float elv = el[b * NN + m0 + ra];
  const int rb = t >> 1, kb = (t & 1) * 16;
  const ushort_t* bph = hThi + (size_t)(n0 + rb) * MTOT + b * NN + kb;
  const ushort_t* bpl = hTlo + (size_t)(n0 + rb) * MTOT + b * NN + kb;
  f32x4 acc[2][4];
#pragma unroll
  for (int mi = 0; mi < 2; ++mi)
#pragma unroll
    for (int ni = 0; ni < 4; ++ni) acc[mi][ni] = (f32x4){0.f, 0.f, 0.f, 0.f};
  __syncthreads();   // ers/wls visible

  for (int k0 = 0; k0 < NN; k0 += 32) {
    uint4 vbh0 = *(const uint4*)(bph + k0);
    uint4 vbh1 = *(const uint4*)(bph + k0 + 8);
    uint4 vbl0 = *(const uint4*)(bpl + k0);
    uint4 vbl1 = *(const uint4*)(bpl + k0 + 8);
    float s[8];
#pragma unroll
    for (int j = 0; j < 8; ++j) {
      float x = elv + ers[k0 + ka + j];
      x = fmaxf(x, 0.01f * x);
      s[j] = __builtin_amdgcn_rcpf(1.0f + __expf(fmaf(x, npinv, npc)));
    }
    uint4 av;
    av.x = pack_rne(s[0], s[1]); av.y = pack_rne(s[2], s[3]);
    av.z = pack_rne(s[4], s[5]); av.w = pack_rne(s[6], s[7]);
    __syncthreads();
    *(uint4*)&Ah[ra * 40 + ka] = av;
    *(uint4*)&Bh[rb * 40 + kb] = vbh0; *(uint4*)&Bh[rb * 40 + kb + 8] = vbh1;
    *(uint4*)&Bl[rb * 40 + kb] = vbl0; *(uint4*)&Bl[rb * 40 + kb + 8] = vbl1;
    __syncthreads();
    bf16x8 af[2], bhf[4], blf[4];
#pragma unroll
    for (int i = 0; i < 2; ++i) af[i] = *(const bf16x8*)&Ah[(wm + i * 16 + ln) * 40 + quad * 8];
#pragma unroll
    for (int i = 0; i < 4; ++i) {
      const int bo = (wn + i * 16 + ln) * 40 + quad * 8;
      bhf[i] = *(const bf16x8*)&Bh[bo];
      blf[i] = *(const bf16x8*)&Bl[bo];
    }
#pragma unroll
    for (int mi = 0; mi < 2; ++mi)
#pragma unroll
      for (int ni = 0; ni < 4; ++ni) {
        acc[mi][ni] = __builtin_amdgcn_mfma_f32_16x16x32_bf16(af[mi], bhf[ni], acc[mi][ni], 0, 0, 0);
        acc[mi][ni] = __builtin_amdgcn_mfma_f32_16x16x32_bf16(af[mi], blf[ni], acc[mi][ni], 0, 0, 0);
      }
  }
#pragma unroll
  for (int mi = 0; mi < 2; ++mi) {
    const int mrl = m0 + wm + mi * 16 + quad * 4;         // row within batch
    const size_t mrow = (size_t)b * NN + mrl;
#pragma unroll
    for (int ni = 0; ni < 4; ++ni) {
      const int c = n0 + wn + ni * 16 + ln;
#pragma unroll
      for (int rr = 0; rr < 4; ++rr) {
        float v = acc[mi][ni][rr];
        if (doElu) v = eluf(v);
        C[(mrow + rr) * Nc + c] = v;
      }
    }
    if (wg) {
#pragma unroll
      for (int rr = 0; rr < 4; ++rr) {
        float vw = 0.f;
#pragma unroll
        for (int ni = 0; ni < 4; ++ni)
          vw = fmaf(acc[mi][ni][rr], wls[wn + ni * 16 + ln], vw);
#pragma unroll
        for (int m = 1; m < 16; m <<= 1) vw += __shfl_xor(vw, m);
        if (ln == 0) atomicAdd(&wv[b * NN + mrl + rr], vw);
      }
    }
  }
}

// ---------------------------------------------------------------------------
// Fused: fc2[b,i,j] = att2(i,j) (fp32) AND out[b,i] = leaky(sum_j att*w + bg).
// One wave per row i; lanes cover 4 consecutive j each (coalesced float4).
// ---------------------------------------------------------------------------
__global__ __launch_bounds__(256) void final_out_fc2(const float* __restrict__ el,
                                                     const float* __restrict__ er,
                                                     const float2* __restrict__ params,
                                                     const float* __restrict__ w,
                                                     const float* __restrict__ bg,
                                                     float* __restrict__ fc2,
                                                     float* __restrict__ out) {
  const int row  = (blockIdx.x * 256 + threadIdx.x) >> 6;  // b*N+i
  const int lane = threadIdx.x & 63;
  const int b = row >> 10;
  const float2 p = params[b];
  const float npinv = -p.y;
  const float npc   = p.x * p.y + 20.0f;
  const float eli = el[row];
  const float* erb = er + (b << 10);
  const float* wb  = w + (b << 10);
  float* fcrow = fc2 + (size_t)row * NN;
  float s = 0.f;
  for (int j = lane * 4; j < NN; j += 256) {
    float4 e4 = *(const float4*)&erb[j];
    float4 w4 = *(const float4*)&wb[j];
    float4 a;
    a.x = __builtin_amdgcn_rcpf(1.0f + __expf(fmaf(leakyf(eli + e4.x), npinv, npc)));
    a.y = __builtin_amdgcn_rcpf(1.0f + __expf(fmaf(leakyf(eli + e4.y), npinv, npc)));
    a.z = __builtin_amdgcn_rcpf(1.0f + __expf(fmaf(leakyf(eli + e4.z), npinv, npc)));
    a.w = __builtin_amdgcn_rcpf(1.0f + __expf(fmaf(leakyf(eli + e4.w), npinv, npc)));
    s += w4.x * a.x + w4.y * a.y + w4.z * a.z + w4.w * a.w;
    *(float4*)&fcrow[j] = a;
  }
#pragma unroll
  for (int off = 32; off > 0; off >>= 1) s += __shfl_down(s, off);
  if (lane == 0) out[row] = leakyf(s + bg[0]);
}

extern "C" void kernel_launch(void* const* d_in, const int* in_sizes, int n_in,
                              void* d_out, int out_size, void* d_ws, size_t ws_size,
                              hipStream_t stream) {
  (void)in_sizes; (void)n_in; (void)out_size; (void)ws_size;
  const float* x  = (const float*)d_in[0];
  const float* W1 = (const float*)d_in[2];
  const float* a1 = (const float*)d_in[3];
  const float* W2 = (const float*)d_in[4];
  const float* a2 = (const float*)d_in[5];
  const float* Wg = (const float*)d_in[6];
  const float* bg = (const float*)d_in[7];

  float* out = (float*)d_out;               // [B,N,1]   32768
  float* fc2 = out + 32768;                 // [B,N,N]   33554432
  float* g2  = fc2 + 33554432;              // [B,N,H2]  4194304

  // Scratch inside the fc2 region (fc2 is written LAST, by final_out_fc2).
  ushort_t* h1Thi = (ushort_t*)fc2;                     // [256][32768]
  ushort_t* h1Tlo = (ushort_t*)(fc2 + 4194304);
  float*    g1    = fc2 + 8388608;                      // [32768][256] fp32
  ushort_t* h2Thi = (ushort_t*)(fc2 + 16777216);        // [128][32768]
  ushort_t* h2Tlo = (ushort_t*)(fc2 + 18874368);

  float* wsf = (float*)d_ws;
  float* el1 = wsf;                          // 32768 each; el1,er1,el2,er2,wv
  float* er1 = wsf + 32768;                  //   contiguous -> single memset
  float* el2 = wsf + 65536;
  float* er2 = wsf + 98304;
  float* wv  = wsf + 131072;
  float2* p1 = (float2*)(wsf + 163840);      // 32 float2
  float2* p2 = (float2*)(wsf + 163904);
  ushort_t* W1Thi = (ushort_t*)(wsf + 163968);   // [256][512]
  ushort_t* W1Tlo = (ushort_t*)(wsf + 229504);
  ushort_t* W2Thi = (ushort_t*)(wsf + 295040);   // [128][256]
  ushort_t* W2Tlo = (ushort_t*)(wsf + 311424);

  dim3 blk(256);
  hipMemsetAsync(wsf, 0, 5u * 32768u * sizeof(float), stream);   // el/er/wv = 0
  transpose_w_split<<<512, blk, 0, stream>>>(W1, W1Thi, W1Tlo, HH1, 9);
  transpose_w_split<<<128, blk, 0, stream>>>(W2, W2Thi, W2Tlo, HH2, 8);
  // Stage 1
  gemm_asplit<HH1><<<512, blk, 0, stream>>>(x, W1Thi, W1Tlo, a1,
                                            h1Thi, h1Tlo, el1, er1, FIN);
  minmax_params<<<32, blk, 0, stream>>>(el1, er1, p1);
  gemm_att2<<<dim3(16, 2, 32), blk, 0, stream>>>(el1, er1, p1, h1Thi, h1Tlo,
                                                 g1, nullptr, nullptr, HH1, 1);
  // Stage 2
  gemm_asplit<HH2><<<512, blk, 0, stream>>>(g1, W2Thi, W2Tlo, a2,
                                            h2Thi, h2Tlo, el2, er2, HH1);
  minmax_params<<<32, blk, 0, stream>>>(el2, er2, p2);
  gemm_att2<<<dim3(16, 1, 32), blk, 0, stream>>>(el2, er2, p2, h2Thi, h2Tlo,
                                                 g2, Wg, wv, HH2, 0);
  // Stage 3: fc2 + out (att recomputed on the fly; wv = g2 @ Wg already fused)
  final_out_fc2<<<8192, blk, 0, stream>>>(el2, er2, p2, wv, bg, fc2, out);
}